// Round 5
// baseline (840.542 us; speedup 1.0000x reference)
//
#include <hip/hip_runtime.h>
#include <stdint.h>

typedef _Float16 half_t;
typedef __attribute__((ext_vector_type(8))) _Float16 half8;
typedef __attribute__((ext_vector_type(4))) _Float16 half4;
typedef __attribute__((ext_vector_type(4))) float floatx4;

#define SEQ 2048
#define NH 16
#define HD 64

#define MFMA16(a, b, c) __builtin_amdgcn_mfma_f32_16x16x16f16(a, b, c, 0, 0, 0)
#define MFMA32K(a, b, c) __builtin_amdgcn_mfma_f32_16x16x32_f16(a, b, c, 0, 0, 0)

// SCALE * log2(e): scores exit QK in log2 domain -> raw v_exp_f32
#define QSCALE 0.1803368801111306f

// ---------------- prep: casts + weight transposes + mask tables -------------
__global__ __launch_bounds__(256) void prep(
    const float* __restrict__ query, const float* __restrict__ key_value,
    const float* __restrict__ Wq, const float* __restrict__ Wkv,
    const float* __restrict__ Wo, half_t* __restrict__ xq,
    half_t* __restrict__ xkv, half_t* __restrict__ wqT,
    half_t* __restrict__ wkvT, half_t* __restrict__ woT,
    uint8_t* __restrict__ tok, uint8_t* __restrict__ tok16,
    uint64_t* __restrict__ maskw, uint32_t* __restrict__ ctrs) {
  int bx = blockIdx.x, tid = threadIdx.x;
  if (bx < 2048) {  // fp32 -> f16 casts, 4096 elements per block
    const float* s; half_t* d; int base;
    if (bx < 1024) { s = query; d = xq; base = bx * 4096; }
    else { s = key_value; d = xkv; base = (bx - 1024) * 4096; }
#pragma unroll
    for (int u = 0; u < 4; ++u) {
      int i = base + u * 1024 + tid * 4;
      floatx4 v = *(const floatx4*)(s + i);
      half4 h;
      h[0] = (half_t)v[0]; h[1] = (half_t)v[1];
      h[2] = (half_t)v[2]; h[3] = (half_t)v[3];
      *(half4*)(d + i) = h;
    }
    return;
  }
  if (bx < 4096) {  // weight transpose+cast, 2 tiles per block
    __shared__ float tile[32][33];
    int tx = tid & 31, ty = tid >> 5;
    const int K = 1024;
#pragma unroll
    for (int u = 0; u < 2; ++u) {
      int t = (bx - 2048) * 2 + u;
      const float* W; half_t* Wt; int N, nt, kt;
      if (t < 1024) { W = Wq; Wt = wqT; N = 1024; nt = t & 31; kt = t >> 5; }
      else if (t < 3072) { int t2 = t - 1024; W = Wkv; Wt = wkvT; N = 2048; nt = t2 & 63; kt = t2 >> 6; }
      else { int t2 = t - 3072; W = Wo; Wt = woT; N = 1024; nt = t2 & 31; kt = t2 >> 5; }
      int n0 = nt * 32, k0 = kt * 32;
#pragma unroll
      for (int i = 0; i < 4; ++i)
        tile[ty + i * 8][tx] = W[(size_t)(k0 + ty + i * 8) * N + n0 + tx];
      __syncthreads();
#pragma unroll
      for (int i = 0; i < 4; ++i)
        Wt[(size_t)(n0 + ty + i * 8) * K + k0 + tx] = (half_t)tile[tx][ty + i * 8];
      __syncthreads();
    }
    return;
  }
  // mask tables (+ counter reset for the fused kernel)
  __shared__ uint8_t slut[2048];
  int ib = bx - 4096;
  if (ib == 0 && tid < 8) ctrs[tid] = 0;
  for (int d = tid; d < 2048; d += 256) {
    int x = d;
    bool ok = true;
    for (int it = 0; it < 7; ++it) { ok &= ((x % 3) != 1); x /= 3; }
    ok &= (x == 0);
    slut[d] = (ok || d <= 64) ? 1 : 0;
  }
  __syncthreads();
  if (ib == 0) {
    if (tid < 64) {  // 64-gran tile activity
      int delta = tid - 32;
      int lo = delta * 64 - 63, hi = delta * 64 + 63;
      uint8_t any = 0;
      for (int x = lo; x <= hi; ++x) {
        int a = x < 0 ? -x : x;
        if (a < 2048) any |= slut[a];
      }
      tok[tid] = any;
    }
    {  // 16-gran subtile activity
      int d16 = tid - 128;
      int ctr = d16 * 16;
      uint8_t any = 0;
      for (int x = ctr - 15; x <= ctr + 15; ++x) {
        int a = x < 0 ? -x : x;
        if (a < 2048) any |= slut[a];
      }
      tok16[tid] = any;
    }
  }
  int g = ib * 256 + tid;  // 0..4095
  int tt = g - 2048;
  uint64_t w = 0;
  for (int jj = 0; jj < 64; ++jj) {
    int d = tt - jj; d = d < 0 ? -d : d;
    if (d < 2048 && slut[d]) w |= (1ull << jj);
  }
  maskw[g] = w;
}

// ---------------- async global->LDS 16B -------------------------------------
__device__ __forceinline__ void cp16(half_t* lds, const half_t* g) {
  __builtin_amdgcn_global_load_lds(
      (const __attribute__((address_space(1))) uint32_t*)g,
      (__attribute__((address_space(3))) uint32_t*)lds, 16, 0, 0);
}

// ---------------- software grid barrier (all 512 blocks resident) -----------
// launch_bounds(512,4) caps VGPR at 128 and dyn-LDS is 48KB -> capacity
// >= 2 blocks/CU * 256 CUs = 512: every block resident, spin cannot deadlock.
// atomicAdd(,0) as the read: device-scope RMW bypasses stale per-XCD L2.
__device__ __forceinline__ void gridbar(uint32_t* ctr, uint32_t target) {
  __threadfence();   // release: publish this thread's writes device-wide
  __syncthreads();
  if (threadIdx.x == 0) {
    atomicAdd(ctr, 1u);
    while (atomicAdd(ctr, 0u) < target) __builtin_amdgcn_s_sleep(16);
  }
  __syncthreads();
  __threadfence();   // acquire: invalidate stale lines before reading peers' data
}

// ---------------- fused qkv-gemm | attention | out-gemm ----------------------
// 512 blocks x 512 threads, 2 sw grid barriers. Inner loops identical to the
// proven standalone kernels; qkv uses 128x256 tiles (8 waves, same per-wave
// code, A staged once per 256 output cols), gemm_out 128x128 tiles. Tiles
// distributed by atomic tickets (reset in prep) -> load-balanced, and sync
// counts stay block-uniform (tickets are block-wide).
__global__ __launch_bounds__(512, 4) void fused(
    const half_t* __restrict__ xq, const half_t* __restrict__ xkv,
    const half_t* __restrict__ wqT, const half_t* __restrict__ wkvT,
    const float* __restrict__ bq, const float* __restrict__ bkv,
    half_t* __restrict__ qout, half_t* __restrict__ kout,
    half_t* __restrict__ vTout, const uint64_t* __restrict__ maskw,
    const uint8_t* __restrict__ tok, const uint8_t* __restrict__ tok16g,
    half_t* __restrict__ ctx, const half_t* __restrict__ woT,
    const float* __restrict__ bo, float* __restrict__ outf,
    uint32_t* ctrs) {
  extern __shared__ char smemraw[];
  __shared__ int s_t;
  __shared__ int list[34];
  __shared__ uint8_t tok16s[256];

  int tid = threadIdx.x;
  int wave = tid >> 6, lane = tid & 63;
  int c = lane & 15, quad = lane >> 4;
  const int K = 1024;

  // ================= phase 1: q+kv projection, 128x256 tiles ================
  {
    half_t* As = (half_t*)smemraw;  // [2][128*32]
    half_t* Bs = As + 8192;         // [2][256*32]
    int wm = (wave >> 2) * 64, wn = (wave & 3) * 64;
    int arow = tid >> 2;
    int akc = ((tid & 3) ^ (arow & 3)) * 8;  // source pre-swizzle (rule 21)
    int csw = c & 3;
    for (;;) {
      if (tid == 0) s_t = (int)atomicAdd(&ctrs[1], 1u);
      __syncthreads();
      int t = s_t;
      __syncthreads();
      if (t >= 384) break;
      int xt = t & 31, y = t >> 5;  // consecutive tickets share the B panel
      bool isq = y < 4;
      const half_t* A = isq ? xq : xkv;
      const half_t* Bt = isq ? wqT : wkvT;
      const float* bias = isq ? bq : bkv;
      int n0 = isq ? y * 256 : (y - 4) * 256;
      int m0 = xt * 128;

      floatx4 acc[4][4] = {};
      cp16(&As[tid * 8], A + (size_t)(m0 + arow) * K + akc);
      cp16(&Bs[tid * 8], Bt + (size_t)(n0 + arow) * K + akc);
      cp16(&Bs[4096 + tid * 8], Bt + (size_t)(n0 + 128 + arow) * K + akc);

      for (int kt = 0; kt < 32; ++kt) {
        __syncthreads();
        if (kt + 1 < 32) {
          int k0 = (kt + 1) * 32;
          int b = (kt + 1) & 1;
          cp16(&As[b * 4096 + tid * 8], A + (size_t)(m0 + arow) * K + k0 + akc);
          cp16(&Bs[b * 8192 + tid * 8], Bt + (size_t)(n0 + arow) * K + k0 + akc);
          cp16(&Bs[b * 8192 + 4096 + tid * 8], Bt + (size_t)(n0 + 128 + arow) * K + k0 + akc);
        }
        int b = kt & 1;
        half8 af[4], bf[4];
#pragma unroll
        for (int mt = 0; mt < 4; ++mt)
          af[mt] = *(const half8*)&As[b * 4096 + (wm + mt * 16 + c) * 32 + ((quad ^ csw) * 8)];
#pragma unroll
        for (int nt = 0; nt < 4; ++nt)
          bf[nt] = *(const half8*)&Bs[b * 8192 + (wn + nt * 16 + c) * 32 + ((quad ^ csw) * 8)];
#pragma unroll
        for (int mt = 0; mt < 4; ++mt)
#pragma unroll
          for (int nt = 0; nt < 4; ++nt)
            acc[mt][nt] = MFMA32K(af[mt], bf[nt], acc[mt][nt]);
      }

      __syncthreads();
      half_t* ep = (half_t*)smemraw;
      int bb = m0 >> 11, sbase = m0 & 2047;
      bool isv = (!isq) && (n0 >= 1024);
      // two 128-col rounds (ep buffer covers 128 cols at a time)
#pragma unroll
      for (int nh = 0; nh < 2; ++nh) {
        if (!isv) {  // q or k: ep[m][n] stride 128 -> [bh][s][d]
          if ((wn >> 7) == nh) {
            int wnl = wn & 127;
#pragma unroll
            for (int nt = 0; nt < 4; ++nt) {
              int nl = wnl + nt * 16 + c;
              float bv = bias[n0 + wn + nt * 16 + c];
#pragma unroll
              for (int mt = 0; mt < 4; ++mt)
#pragma unroll
                for (int r = 0; r < 4; ++r) {
                  int ml = wm + mt * 16 + quad * 4 + r;
                  float v = acc[mt][nt][r] + bv;
                  if (isq) v *= QSCALE;
                  ep[ml * 128 + nl] = (half_t)v;
                }
            }
          }
          __syncthreads();
          half_t* outp = isq ? qout : kout;
#pragma unroll
          for (int rd = 0; rd < 4; ++rd) {
            int id = rd * 512 + tid;  // 2048 chunks of 16B
            int ml = id >> 4, ch = id & 15;
            int ng = n0 + nh * 128 + ch * 8;
            int h = ng >> 6, d0 = ng & 63;
            half8 v = *(const half8*)&ep[ml * 128 + ch * 8];
            *(half8*)(outp + ((size_t)(bb * 16 + h) * SEQ + sbase + ml) * 64 + d0) = v;
          }
          __syncthreads();
        } else {  // v: ep[n][m] stride 136 -> [bh][d][s]
          if ((wn >> 7) == nh) {
            int wnl = wn & 127;
#pragma unroll
            for (int nt = 0; nt < 4; ++nt) {
              int nl = wnl + nt * 16 + c;
              float bv = bias[n0 + wn + nt * 16 + c];
#pragma unroll
              for (int mt = 0; mt < 4; ++mt) {
                int ml = wm + mt * 16 + quad * 4;
                half4 hv;
#pragma unroll
                for (int r = 0; r < 4; ++r) hv[r] = (half_t)(acc[mt][nt][r] + bv);
                *(half4*)&ep[nl * 136 + ml] = hv;
              }
            }
          }
          __syncthreads();
#pragma unroll
          for (int rd = 0; rd < 4; ++rd) {
            int id = rd * 512 + tid;
            int nl = id >> 4, mc = id & 15;
            int ng = n0 + nh * 128 + nl;
            int h = (ng >> 6) & 15, d = ng & 63;
            half8 v = *(const half8*)&ep[nl * 136 + mc * 8];
            *(half8*)(vTout + ((size_t)(bb * 16 + h) * 64 + d) * SEQ + sbase + mc * 8) = v;
          }
          __syncthreads();
        }
      }
    }
  }

  gridbar(&ctrs[0], 512);

  // ================= phase 2: masked flash attention (r4 body) ==============
  {
    half_t* kT = (half_t*)smemraw;  // 64*64
    half_t* vT = kT + 4096;         // 64*64
    half_t* ot = vT + 4096;         // 128*72
    int id = blockIdx.x;
    int bh = (id & 7) * 4 + ((id >> 3) & 3);  // XCD-major: bh fixed per XCD
    int it128 = id >> 5;
    int i0 = it128 << 7;
    const half_t* qbase = qout + (size_t)bh * SEQ * HD;
    const half_t* kg = kout + (size_t)bh * SEQ * HD;
    const half_t* vg = vTout + (size_t)bh * HD * SEQ;

    if (tid < 256) tok16s[tid] = tok16g[tid];
    if (wave == 0) {
      int jt = lane;
      int base = i0 >> 6;
      bool act = (jt < 32) &&
                 (tok[(jt - base) + 32] | tok[(jt - base - 1) + 32]);
      unsigned long long bal = __ballot(act);
      if (act) {
        int pre = __popcll(bal & ((1ull << jt) - 1));
        list[1 + pre] = jt << 6;
      }
      if (lane == 0) list[0] = __popcll(bal);
    }

    int i_row = i0 + wave * 16 + c;
    int it16 = (i0 >> 4) + wave;
    half8 qf0 = *(const half8*)(qbase + (size_t)i_row * 64 + quad * 8);
    half8 qf1 = *(const half8*)(qbase + (size_t)i_row * 64 + 32 + quad * 8);

    floatx4 oacc[4] = {};
    floatx4 lacc = {};
    half4 ones;
    ones[0] = (half_t)1.f; ones[1] = (half_t)1.f;
    ones[2] = (half_t)1.f; ones[3] = (half_t)1.f;

    int srow = tid >> 3;  // 0..63
    int sch = tid & 7;    // 0..7
    int ssw = srow & 7;

    __syncthreads();  // list + tok16s ready
    int nact = list[0];
    int j0 = list[1];

    half8 kr = *(const half8*)(kg + (size_t)(j0 + srow) * 64 + sch * 8);
    half8 vr = *(const half8*)(vg + (size_t)srow * SEQ + j0 + sch * 8);
    uint64_t wcur = maskw[(i_row - j0) + 2048];

    for (int ti = 0; ti < nact; ++ti) {
      int bidx = (j0 >> 4) - it16 + 128;
      __syncthreads();  // A: previous compute done
      *(half8*)&kT[srow * 64 + ((sch ^ ssw) * 8)] = kr;
      *(half8*)&vT[srow * 64 + ((sch ^ ssw) * 8)] = vr;
      int j0n = (ti + 1 < nact) ? list[2 + ti] : j0;
      __syncthreads();  // B: ds_writes visible

      // T14: issue next-tile loads AFTER the barrier
      uint64_t wnext = wcur;
      if (ti + 1 < nact) {
        kr = *(const half8*)(kg + (size_t)(j0n + srow) * 64 + sch * 8);
        vr = *(const half8*)(vg + (size_t)srow * SEQ + j0n + sch * 8);
        wnext = maskw[(i_row - j0n) + 2048];
      }

      uint32_t wlo = (uint32_t)(wcur >> (4 * quad));
      uint32_t whi = (uint32_t)(wcur >> (32 + 4 * quad));
#pragma unroll
      for (int jt = 0; jt < 4; ++jt) {
        if (!tok16s[bidx + jt]) continue;  // wave-uniform subtile skip
        int row = jt * 16 + c;
        int sw = c & 7;
        half8 a0 = *(const half8*)&kT[row * 64 + ((quad ^ sw) * 8)];
        half8 a1 = *(const half8*)&kT[row * 64 + (((4 + quad) ^ sw) * 8)];
        floatx4 tt = {};
        tt = MFMA32K(a0, qf0, tt);
        tt = MFMA32K(a1, qf1, tt);
        uint32_t ww = (jt < 2) ? wlo : whi;
#pragma unroll
        for (int r = 0; r < 4; ++r) {
          float p = __builtin_exp2f(tt[r]);
          int bitpos = 16 * (jt & 1) + r;
          uint32_t msk = (uint32_t)(((int)(ww << (31 - bitpos))) >> 31);
          tt[r] = __uint_as_float(__float_as_uint(p) & msk);
        }
        auto lo = __builtin_amdgcn_cvt_pkrtz(tt[0], tt[1]);
        auto hi = __builtin_amdgcn_cvt_pkrtz(tt[2], tt[3]);
        half4 pb;
        pb[0] = lo[0]; pb[1] = lo[1]; pb[2] = hi[0]; pb[3] = hi[1];
        lacc = MFMA16(ones, pb, lacc);
#pragma unroll
        for (int mt = 0; mt < 4; ++mt) {
          int drow = mt * 16 + c;
          int ch = 2 * jt + (quad >> 1);
          half4 a = *(const half4*)&vT[drow * 64 + ((ch ^ sw) * 8) + (quad & 1) * 4];
          oacc[mt] = MFMA16(a, pb, oacc[mt]);
        }
      }
      wcur = wnext;
      j0 = j0n;
    }

    // epilogue: normalize, transpose via LDS, coalesced ctx write
    float inv_l = 1.0f / lacc[0];
#pragma unroll
    for (int mt = 0; mt < 4; ++mt)
#pragma unroll
      for (int r = 0; r < 4; ++r)
        ot[(wave * 16 + c) * 72 + mt * 16 + 4 * quad + r] = (half_t)(oacc[mt][r] * inv_l);
    __syncthreads();
    {
      int row = tid >> 2, chq = tid & 3;  // 128 rows x 4 chunk-pairs
      int b = bh >> 4, h = bh & 15;
      size_t base = (((size_t)(b * SEQ + i0 + row) * NH) + h) * 64 + chq * 16;
      half8 v0 = *(const half8*)&ot[row * 72 + chq * 16];
      half8 v1 = *(const half8*)&ot[row * 72 + chq * 16 + 8];
      *(half8*)(ctx + base) = v0;
      *(half8*)(ctx + base + 8) = v1;
    }
  }

  gridbar(&ctrs[0], 1024);

  // ================= phase 3: out-projection, 128x128 tiles =================
  {
    half_t* As = (half_t*)smemraw;  // [2][128*32]
    half_t* Bs = As + 8192;         // [2][128*32]
    int wm = (wave >> 2) * 64, wn = (wave & 3) * 32;
    int arow = tid >> 2;
    int akc = ((tid & 3) ^ (arow & 3)) * 8;
    int csw = c & 3;
    for (;;) {
      if (tid == 0) s_t = (int)atomicAdd(&ctrs[2], 1u);
      __syncthreads();
      int t = s_t;
      __syncthreads();
      if (t >= 256) break;
      int m0 = (t & 31) * 128, n0 = (t >> 5) * 128;

      floatx4 acc[4][2] = {};
      cp16(&As[tid * 8], ctx + (size_t)(m0 + arow) * K + akc);
      cp16(&Bs[tid * 8], woT + (size_t)(n0 + arow) * K + akc);

      for (int kt = 0; kt < 32; ++kt) {
        __syncthreads();
        if (kt + 1 < 32) {
          int k0 = (kt + 1) * 32;
          int b = (kt + 1) & 1;
          cp16(&As[b * 4096 + tid * 8], ctx + (size_t)(m0 + arow) * K + k0 + akc);
          cp16(&Bs[b * 4096 + tid * 8], woT + (size_t)(n0 + arow) * K + k0 + akc);
        }
        int b = kt & 1;
        half8 af[4], bf[2];
#pragma unroll
        for (int mt = 0; mt < 4; ++mt)
          af[mt] = *(const half8*)&As[b * 4096 + (wm + mt * 16 + c) * 32 + ((quad ^ csw) * 8)];
#pragma unroll
        for (int nt = 0; nt < 2; ++nt)
          bf[nt] = *(const half8*)&Bs[b * 4096 + (wn + nt * 16 + c) * 32 + ((quad ^ csw) * 8)];
#pragma unroll
        for (int mt = 0; mt < 4; ++mt)
#pragma unroll
          for (int nt = 0; nt < 2; ++nt)
            acc[mt][nt] = MFMA32K(af[mt], bf[nt], acc[mt][nt]);
      }
      __syncthreads();  // keep LDS write (next ticket) / read ordering safe

#pragma unroll
      for (int nt = 0; nt < 2; ++nt) {
        int n = n0 + wn + nt * 16 + c;
        float bv = bo[n];
#pragma unroll
        for (int mt = 0; mt < 4; ++mt)
#pragma unroll
          for (int r = 0; r < 4; ++r) {
            int m = m0 + wm + mt * 16 + quad * 4 + r;
            outf[(size_t)m * 1024 + n] = acc[mt][nt][r] + bv;
          }
      }
    }
  }
}

// ---------------- launch -----------------------------------------------------
extern "C" void kernel_launch(void* const* d_in, const int* in_sizes, int n_in,
                              void* d_out, int out_size, void* d_ws, size_t ws_size,
                              hipStream_t stream) {
  const float* query = (const float*)d_in[0];
  const float* key_value = (const float*)d_in[1];
  const float* Wq = (const float*)d_in[2];
  const float* bq = (const float*)d_in[3];
  const float* Wkv = (const float*)d_in[4];
  const float* bkv = (const float*)d_in[5];
  const float* Wo = (const float*)d_in[6];
  const float* bo = (const float*)d_in[7];

  char* ws = (char*)d_ws;
  uint8_t* tok = (uint8_t*)ws;               // 64 B
  uint32_t* ctrs = (uint32_t*)(ws + 512);    // 32 B: [0] barrier, [1] tk_qkv, [2] tk_out
  uint8_t* tok16 = (uint8_t*)(ws + 1024);    // 256 B
  uint64_t* maskw = (uint64_t*)(ws + 4096);  // 32KB
  const size_t MB = 1ull << 20;
  half_t* xq = (half_t*)(ws + 1 * MB);    // 8MB; reused as ctx after qkv gemm
  half_t* xkv = (half_t*)(ws + 9 * MB);   // 8MB
  half_t* wqT = (half_t*)(ws + 17 * MB);  // 2MB
  half_t* wkvT = (half_t*)(ws + 19 * MB); // 4MB
  half_t* woT = (half_t*)(ws + 23 * MB);  // 2MB
  half_t* qbuf = (half_t*)(ws + 25 * MB); // 8MB
  half_t* kbuf = (half_t*)(ws + 33 * MB); // 8MB
  half_t* vTg = (half_t*)(ws + 41 * MB);  // 8MB ([bh][d][s])
  half_t* ctx = xq;                       // alias (xq dead after proj phase)

  hipLaunchKernelGGL(prep, dim3(4112), dim3(256), 0, stream,
                     query, key_value, Wq, Wkv, Wo, xq, xkv, wqT, wkvT, woT,
                     tok, tok16, maskw, ctrs);
  hipLaunchKernelGGL(fused, dim3(512), dim3(512), 49152, stream,
                     xq, xkv, wqT, wkvT, bq, bkv, qbuf, kbuf, vTg,
                     maskw, tok, tok16, ctx, woT, bo, (float*)d_out, ctrs);
}

// Round 6
// 734.812 us; speedup vs baseline: 1.1439x; 1.1439x over previous
//
#include <hip/hip_runtime.h>
#include <stdint.h>

typedef _Float16 half_t;
typedef __attribute__((ext_vector_type(8))) _Float16 half8;
typedef __attribute__((ext_vector_type(4))) _Float16 half4;
typedef __attribute__((ext_vector_type(4))) float floatx4;

#define SEQ 2048
#define NH 16
#define HD 64

#define MFMA16(a, b, c) __builtin_amdgcn_mfma_f32_16x16x16f16(a, b, c, 0, 0, 0)
#define MFMA32K(a, b, c) __builtin_amdgcn_mfma_f32_16x16x32_f16(a, b, c, 0, 0, 0)

// SCALE * log2(e): scores exit QK in log2 domain -> raw v_exp_f32
#define QSCALE 0.1803368801111306f

// ---------------- prep: casts + weight transposes + mask tables -------------
__global__ __launch_bounds__(256) void prep(
    const float* __restrict__ query, const float* __restrict__ key_value,
    const float* __restrict__ Wq, const float* __restrict__ Wkv,
    const float* __restrict__ Wo, half_t* __restrict__ xq,
    half_t* __restrict__ xkv, half_t* __restrict__ wqT,
    half_t* __restrict__ wkvT, half_t* __restrict__ woT,
    uint8_t* __restrict__ tok, uint8_t* __restrict__ tok16,
    uint64_t* __restrict__ maskw, uint32_t* __restrict__ ctrs) {
  int bx = blockIdx.x, tid = threadIdx.x;
  if (bx < 2048) {  // fp32 -> f16 casts, 4096 elements per block
    const float* s; half_t* d; int base;
    if (bx < 1024) { s = query; d = xq; base = bx * 4096; }
    else { s = key_value; d = xkv; base = (bx - 1024) * 4096; }
#pragma unroll
    for (int u = 0; u < 4; ++u) {
      int i = base + u * 1024 + tid * 4;
      floatx4 v = *(const floatx4*)(s + i);
      half4 h;
      h[0] = (half_t)v[0]; h[1] = (half_t)v[1];
      h[2] = (half_t)v[2]; h[3] = (half_t)v[3];
      *(half4*)(d + i) = h;
    }
    return;
  }
  if (bx < 4096) {  // weight transpose+cast, 2 tiles per block
    __shared__ float tile[32][33];
    int tx = tid & 31, ty = tid >> 5;
    const int K = 1024;
#pragma unroll
    for (int u = 0; u < 2; ++u) {
      int t = (bx - 2048) * 2 + u;
      const float* W; half_t* Wt; int N, nt, kt;
      if (t < 1024) { W = Wq; Wt = wqT; N = 1024; nt = t & 31; kt = t >> 5; }
      else if (t < 3072) { int t2 = t - 1024; W = Wkv; Wt = wkvT; N = 2048; nt = t2 & 63; kt = t2 >> 6; }
      else { int t2 = t - 3072; W = Wo; Wt = woT; N = 1024; nt = t2 & 31; kt = t2 >> 5; }
      int n0 = nt * 32, k0 = kt * 32;
#pragma unroll
      for (int i = 0; i < 4; ++i)
        tile[ty + i * 8][tx] = W[(size_t)(k0 + ty + i * 8) * N + n0 + tx];
      __syncthreads();
#pragma unroll
      for (int i = 0; i < 4; ++i)
        Wt[(size_t)(n0 + ty + i * 8) * K + k0 + tx] = (half_t)tile[tx][ty + i * 8];
      __syncthreads();
    }
    return;
  }
  // mask tables (+ counter reset for the fused kernel)
  __shared__ uint8_t slut[2048];
  int ib = bx - 4096;
  if (ib == 0 && tid < 8) ctrs[tid] = 0;
  for (int d = tid; d < 2048; d += 256) {
    int x = d;
    bool ok = true;
    for (int it = 0; it < 7; ++it) { ok &= ((x % 3) != 1); x /= 3; }
    ok &= (x == 0);
    slut[d] = (ok || d <= 64) ? 1 : 0;
  }
  __syncthreads();
  if (ib == 0) {
    if (tid < 64) {  // 64-gran tile activity
      int delta = tid - 32;
      int lo = delta * 64 - 63, hi = delta * 64 + 63;
      uint8_t any = 0;
      for (int x = lo; x <= hi; ++x) {
        int a = x < 0 ? -x : x;
        if (a < 2048) any |= slut[a];
      }
      tok[tid] = any;
    }
    {  // 16-gran subtile activity
      int d16 = tid - 128;
      int ctr = d16 * 16;
      uint8_t any = 0;
      for (int x = ctr - 15; x <= ctr + 15; ++x) {
        int a = x < 0 ? -x : x;
        if (a < 2048) any |= slut[a];
      }
      tok16[tid] = any;
    }
  }
  int g = ib * 256 + tid;  // 0..4095
  int tt = g - 2048;
  uint64_t w = 0;
  for (int jj = 0; jj < 64; ++jj) {
    int d = tt - jj; d = d < 0 ? -d : d;
    if (d < 2048 && slut[d]) w |= (1ull << jj);
  }
  maskw[g] = w;
}

// ---------------- async global->LDS 16B -------------------------------------
__device__ __forceinline__ void cp16(half_t* lds, const half_t* g) {
  __builtin_amdgcn_global_load_lds(
      (const __attribute__((address_space(1))) uint32_t*)g,
      (__attribute__((address_space(3))) uint32_t*)lds, 16, 0, 0);
}

// ---------------- software grid barrier (all 512 blocks resident) -----------
// launch_bounds(512,2): empirically (r5: arg 4 -> 64 VGPR) the 2nd arg is
// min BLOCKS/CU -> 2 blocks/CU = 16 waves/CU -> VGPR cap 128 (no spill at
// ~100 natural demand) and compiler-guaranteed residency for all 512 blocks
// (LDS 48KB dyn * 2 = 97KB <= 160KB). Spin cannot deadlock.
__device__ __forceinline__ void gridbar(uint32_t* ctr, uint32_t target) {
  __threadfence();   // release: publish writes device-wide
  __syncthreads();
  if (threadIdx.x == 0) {
    atomicAdd(ctr, 1u);
    while (atomicAdd(ctr, 0u) < target) __builtin_amdgcn_s_sleep(16);
  }
  __syncthreads();
  __threadfence();   // acquire
}

// ---------------- fused qkv-gemm | attention | out-gemm ----------------------
// 512 blocks x 512 threads, 2 sw grid barriers (scheme validated r5 — passed
// correctness; r5's 743us was pure VGPR-spill from the 64-reg cap).
// Phase 1: 384 static 128x256 tiles. Phase 2: r4 attn body (validated).
// Phase 3: 512 static 128x64 tiles (1 per block, zero idle).
__global__ __launch_bounds__(512, 2) void fused(
    const half_t* __restrict__ xq, const half_t* __restrict__ xkv,
    const half_t* __restrict__ wqT, const half_t* __restrict__ wkvT,
    const float* __restrict__ bq, const float* __restrict__ bkv,
    half_t* __restrict__ qout, half_t* __restrict__ kout,
    half_t* __restrict__ vTout, const uint64_t* __restrict__ maskw,
    const uint8_t* __restrict__ tok, const uint8_t* __restrict__ tok16g,
    half_t* __restrict__ ctx, const half_t* __restrict__ woT,
    const float* __restrict__ bo, float* __restrict__ outf,
    uint32_t* ctrs) {
  extern __shared__ char smemraw[];
  __shared__ int list[34];
  __shared__ uint8_t tok16s[256];

  int tid = threadIdx.x;
  int wave = tid >> 6, lane = tid & 63;
  int c = lane & 15, quad = lane >> 4;
  const int K = 1024;

  // ================= phase 1: q+kv projection, 128x256 tiles ================
  {
    int t = blockIdx.x;
    if (t < 384) {
      half_t* As = (half_t*)smemraw;  // [2][128*32]
      half_t* Bs = As + 8192;         // [2][256*32]
      int wm = (wave >> 2) * 64, wn = (wave & 3) * 64;
      int arow = tid >> 2;
      int akc = ((tid & 3) ^ (arow & 3)) * 8;  // source pre-swizzle (rule 21)
      int csw = c & 3;
      int xt = t & 31, y = t >> 5;  // consecutive blocks share the B panel
      bool isq = y < 4;
      const half_t* A = isq ? xq : xkv;
      const half_t* Bt = isq ? wqT : wkvT;
      const float* bias = isq ? bq : bkv;
      int n0 = isq ? y * 256 : (y - 4) * 256;
      int m0 = xt * 128;

      floatx4 acc[4][4] = {};
      cp16(&As[tid * 8], A + (size_t)(m0 + arow) * K + akc);
      cp16(&Bs[tid * 8], Bt + (size_t)(n0 + arow) * K + akc);
      cp16(&Bs[4096 + tid * 8], Bt + (size_t)(n0 + 128 + arow) * K + akc);

      for (int kt = 0; kt < 32; ++kt) {
        __syncthreads();
        if (kt + 1 < 32) {
          int k0 = (kt + 1) * 32;
          int b = (kt + 1) & 1;
          cp16(&As[b * 4096 + tid * 8], A + (size_t)(m0 + arow) * K + k0 + akc);
          cp16(&Bs[b * 8192 + tid * 8], Bt + (size_t)(n0 + arow) * K + k0 + akc);
          cp16(&Bs[b * 8192 + 4096 + tid * 8], Bt + (size_t)(n0 + 128 + arow) * K + k0 + akc);
        }
        int b = kt & 1;
        half8 af[4], bf[4];
#pragma unroll
        for (int mt = 0; mt < 4; ++mt)
          af[mt] = *(const half8*)&As[b * 4096 + (wm + mt * 16 + c) * 32 + ((quad ^ csw) * 8)];
#pragma unroll
        for (int nt = 0; nt < 4; ++nt)
          bf[nt] = *(const half8*)&Bs[b * 8192 + (wn + nt * 16 + c) * 32 + ((quad ^ csw) * 8)];
#pragma unroll
        for (int mt = 0; mt < 4; ++mt)
#pragma unroll
          for (int nt = 0; nt < 4; ++nt)
            acc[mt][nt] = MFMA32K(af[mt], bf[nt], acc[mt][nt]);
      }

      __syncthreads();
      half_t* ep = (half_t*)smemraw;
      int bb = m0 >> 11, sbase = m0 & 2047;
      bool isv = (!isq) && (n0 >= 1024);
      // two 128-col rounds (ep buffer covers 128 cols at a time)
#pragma unroll
      for (int nh = 0; nh < 2; ++nh) {
        if (!isv) {  // q or k: ep[m][n] stride 128 -> [bh][s][d]
          if ((wn >> 7) == nh) {
            int wnl = wn & 127;
#pragma unroll
            for (int nt = 0; nt < 4; ++nt) {
              int nl = wnl + nt * 16 + c;
              float bv = bias[n0 + wn + nt * 16 + c];
#pragma unroll
              for (int mt = 0; mt < 4; ++mt)
#pragma unroll
                for (int r = 0; r < 4; ++r) {
                  int ml = wm + mt * 16 + quad * 4 + r;
                  float v = acc[mt][nt][r] + bv;
                  if (isq) v *= QSCALE;
                  ep[ml * 128 + nl] = (half_t)v;
                }
            }
          }
          __syncthreads();
          half_t* outp = isq ? qout : kout;
#pragma unroll
          for (int rd = 0; rd < 4; ++rd) {
            int id = rd * 512 + tid;  // 2048 chunks of 16B
            int ml = id >> 4, ch = id & 15;
            int ng = n0 + nh * 128 + ch * 8;
            int h = ng >> 6, d0 = ng & 63;
            half8 v = *(const half8*)&ep[ml * 128 + ch * 8];
            *(half8*)(outp + ((size_t)(bb * 16 + h) * SEQ + sbase + ml) * 64 + d0) = v;
          }
          __syncthreads();
        } else {  // v: ep[n][m] stride 136 -> [bh][d][s]
          if ((wn >> 7) == nh) {
            int wnl = wn & 127;
#pragma unroll
            for (int nt = 0; nt < 4; ++nt) {
              int nl = wnl + nt * 16 + c;
              float bv = bias[n0 + wn + nt * 16 + c];
#pragma unroll
              for (int mt = 0; mt < 4; ++mt) {
                int ml = wm + mt * 16 + quad * 4;
                half4 hv;
#pragma unroll
                for (int r = 0; r < 4; ++r) hv[r] = (half_t)(acc[mt][nt][r] + bv);
                *(half4*)&ep[nl * 136 + ml] = hv;
              }
            }
          }
          __syncthreads();
#pragma unroll
          for (int rd = 0; rd < 4; ++rd) {
            int id = rd * 512 + tid;
            int nl = id >> 4, mc = id & 15;
            int ng = n0 + nh * 128 + nl;
            int h = (ng >> 6) & 15, d = ng & 63;
            half8 v = *(const half8*)&ep[nl * 136 + mc * 8];
            *(half8*)(vTout + ((size_t)(bb * 16 + h) * 64 + d) * SEQ + sbase + mc * 8) = v;
          }
          __syncthreads();
        }
      }
    }
  }

  gridbar(&ctrs[0], 512);

  // ================= phase 2: masked flash attention (r4 body) ==============
  {
    half_t* kT = (half_t*)smemraw;  // 64*64
    half_t* vT = kT + 4096;         // 64*64
    half_t* ot = vT + 4096;         // 128*72
    int id = blockIdx.x;
    int bh = (id & 7) * 4 + ((id >> 3) & 3);  // XCD-major: bh fixed per XCD
    int it128 = id >> 5;
    int i0 = it128 << 7;
    const half_t* qbase = qout + (size_t)bh * SEQ * HD;
    const half_t* kg = kout + (size_t)bh * SEQ * HD;
    const half_t* vg = vTout + (size_t)bh * HD * SEQ;

    if (tid < 256) tok16s[tid] = tok16g[tid];
    if (wave == 0) {
      int jt = lane;
      int base = i0 >> 6;
      bool act = (jt < 32) &&
                 (tok[(jt - base) + 32] | tok[(jt - base - 1) + 32]);
      unsigned long long bal = __ballot(act);
      if (act) {
        int pre = __popcll(bal & ((1ull << jt) - 1));
        list[1 + pre] = jt << 6;
      }
      if (lane == 0) list[0] = __popcll(bal);
    }

    int i_row = i0 + wave * 16 + c;
    int it16 = (i0 >> 4) + wave;
    half8 qf0 = *(const half8*)(qbase + (size_t)i_row * 64 + quad * 8);
    half8 qf1 = *(const half8*)(qbase + (size_t)i_row * 64 + 32 + quad * 8);

    floatx4 oacc[4] = {};
    floatx4 lacc = {};
    half4 ones;
    ones[0] = (half_t)1.f; ones[1] = (half_t)1.f;
    ones[2] = (half_t)1.f; ones[3] = (half_t)1.f;

    int srow = tid >> 3;  // 0..63
    int sch = tid & 7;    // 0..7
    int ssw = srow & 7;

    __syncthreads();  // list + tok16s ready
    int nact = list[0];
    int j0 = list[1];

    half8 kr = *(const half8*)(kg + (size_t)(j0 + srow) * 64 + sch * 8);
    half8 vr = *(const half8*)(vg + (size_t)srow * SEQ + j0 + sch * 8);
    uint64_t wcur = maskw[(i_row - j0) + 2048];

    for (int ti = 0; ti < nact; ++ti) {
      int bidx = (j0 >> 4) - it16 + 128;
      __syncthreads();  // A: previous compute done
      *(half8*)&kT[srow * 64 + ((sch ^ ssw) * 8)] = kr;
      *(half8*)&vT[srow * 64 + ((sch ^ ssw) * 8)] = vr;
      int j0n = (ti + 1 < nact) ? list[2 + ti] : j0;
      __syncthreads();  // B: ds_writes visible

      // T14: issue next-tile loads AFTER the barrier
      uint64_t wnext = wcur;
      if (ti + 1 < nact) {
        kr = *(const half8*)(kg + (size_t)(j0n + srow) * 64 + sch * 8);
        vr = *(const half8*)(vg + (size_t)srow * SEQ + j0n + sch * 8);
        wnext = maskw[(i_row - j0n) + 2048];
      }

      uint32_t wlo = (uint32_t)(wcur >> (4 * quad));
      uint32_t whi = (uint32_t)(wcur >> (32 + 4 * quad));
#pragma unroll
      for (int jt = 0; jt < 4; ++jt) {
        if (!tok16s[bidx + jt]) continue;  // wave-uniform subtile skip
        int row = jt * 16 + c;
        int sw = c & 7;
        half8 a0 = *(const half8*)&kT[row * 64 + ((quad ^ sw) * 8)];
        half8 a1 = *(const half8*)&kT[row * 64 + (((4 + quad) ^ sw) * 8)];
        floatx4 tt = {};
        tt = MFMA32K(a0, qf0, tt);
        tt = MFMA32K(a1, qf1, tt);
        uint32_t ww = (jt < 2) ? wlo : whi;
#pragma unroll
        for (int r = 0; r < 4; ++r) {
          float p = __builtin_exp2f(tt[r]);
          int bitpos = 16 * (jt & 1) + r;
          uint32_t msk = (uint32_t)(((int)(ww << (31 - bitpos))) >> 31);
          tt[r] = __uint_as_float(__float_as_uint(p) & msk);
        }
        auto lo = __builtin_amdgcn_cvt_pkrtz(tt[0], tt[1]);
        auto hi = __builtin_amdgcn_cvt_pkrtz(tt[2], tt[3]);
        half4 pb;
        pb[0] = lo[0]; pb[1] = lo[1]; pb[2] = hi[0]; pb[3] = hi[1];
        lacc = MFMA16(ones, pb, lacc);
#pragma unroll
        for (int mt = 0; mt < 4; ++mt) {
          int drow = mt * 16 + c;
          int ch = 2 * jt + (quad >> 1);
          half4 a = *(const half4*)&vT[drow * 64 + ((ch ^ sw) * 8) + (quad & 1) * 4];
          oacc[mt] = MFMA16(a, pb, oacc[mt]);
        }
      }
      wcur = wnext;
      j0 = j0n;
    }

    // epilogue: normalize, transpose via LDS, coalesced ctx write
    float inv_l = 1.0f / lacc[0];
#pragma unroll
    for (int mt = 0; mt < 4; ++mt)
#pragma unroll
      for (int r = 0; r < 4; ++r)
        ot[(wave * 16 + c) * 72 + mt * 16 + 4 * quad + r] = (half_t)(oacc[mt][r] * inv_l);
    __syncthreads();
    {
      int row = tid >> 2, chq = tid & 3;  // 128 rows x 4 chunk-pairs
      int b = bh >> 4, h = bh & 15;
      size_t base = (((size_t)(b * SEQ + i0 + row) * NH) + h) * 64 + chq * 16;
      half8 v0 = *(const half8*)&ot[row * 72 + chq * 16];
      half8 v1 = *(const half8*)&ot[row * 72 + chq * 16 + 8];
      *(half8*)(ctx + base) = v0;
      *(half8*)(ctx + base + 8) = v1;
    }
  }

  gridbar(&ctrs[0], 1024);

  // ================= phase 3: out-projection, 512 x (128x64) ================
  {
    half_t* As = (half_t*)smemraw;  // [2][128*32]
    half_t* Bs = As + 8192;         // [2][64*32]
    int t = blockIdx.x;             // exactly one tile per block
    int m0 = (t & 31) * 128, n0 = (t >> 5) * 64;
    int wm = (wave >> 1) * 32, wn = (wave & 1) * 32;
    int arow = tid >> 2;
    int akc = ((tid & 3) ^ (arow & 3)) * 8;
    int csw = c & 3;
    int brow = tid >> 2;  // 0..63 for tid<256

    floatx4 acc[2][2] = {};
    cp16(&As[tid * 8], ctx + (size_t)(m0 + arow) * K + akc);
    if (tid < 256) cp16(&Bs[tid * 8], woT + (size_t)(n0 + brow) * K + akc);

    for (int kt = 0; kt < 32; ++kt) {
      __syncthreads();
      if (kt + 1 < 32) {
        int k0 = (kt + 1) * 32;
        int b = (kt + 1) & 1;
        cp16(&As[b * 4096 + tid * 8], ctx + (size_t)(m0 + arow) * K + k0 + akc);
        if (tid < 256) cp16(&Bs[b * 2048 + tid * 8], woT + (size_t)(n0 + brow) * K + k0 + akc);
      }
      int b = kt & 1;
      half8 af[2], bf[2];
#pragma unroll
      for (int mt = 0; mt < 2; ++mt)
        af[mt] = *(const half8*)&As[b * 4096 + (wm + mt * 16 + c) * 32 + ((quad ^ csw) * 8)];
#pragma unroll
      for (int nt = 0; nt < 2; ++nt)
        bf[nt] = *(const half8*)&Bs[b * 2048 + (wn + nt * 16 + c) * 32 + ((quad ^ csw) * 8)];
#pragma unroll
      for (int mt = 0; mt < 2; ++mt)
#pragma unroll
        for (int nt = 0; nt < 2; ++nt)
          acc[mt][nt] = MFMA32K(af[mt], bf[nt], acc[mt][nt]);
    }

#pragma unroll
    for (int nt = 0; nt < 2; ++nt) {
      int n = n0 + wn + nt * 16 + c;
      float bv = bo[n];
#pragma unroll
      for (int mt = 0; mt < 2; ++mt)
#pragma unroll
        for (int r = 0; r < 4; ++r) {
          int m = m0 + wm + mt * 16 + quad * 4 + r;
          outf[(size_t)m * 1024 + n] = acc[mt][nt][r] + bv;
        }
    }
  }
}

// ---------------- launch -----------------------------------------------------
extern "C" void kernel_launch(void* const* d_in, const int* in_sizes, int n_in,
                              void* d_out, int out_size, void* d_ws, size_t ws_size,
                              hipStream_t stream) {
  const float* query = (const float*)d_in[0];
  const float* key_value = (const float*)d_in[1];
  const float* Wq = (const float*)d_in[2];
  const float* bq = (const float*)d_in[3];
  const float* Wkv = (const float*)d_in[4];
  const float* bkv = (const float*)d_in[5];
  const float* Wo = (const float*)d_in[6];
  const float* bo = (const float*)d_in[7];

  char* ws = (char*)d_ws;
  uint8_t* tok = (uint8_t*)ws;               // 64 B
  uint32_t* ctrs = (uint32_t*)(ws + 512);    // 32 B: [0] barrier
  uint8_t* tok16 = (uint8_t*)(ws + 1024);    // 256 B
  uint64_t* maskw = (uint64_t*)(ws + 4096);  // 32KB
  const size_t MB = 1ull << 20;
  half_t* xq = (half_t*)(ws + 1 * MB);    // 8MB; reused as ctx after qkv phase
  half_t* xkv = (half_t*)(ws + 9 * MB);   // 8MB
  half_t* wqT = (half_t*)(ws + 17 * MB);  // 2MB
  half_t* wkvT = (half_t*)(ws + 19 * MB); // 4MB
  half_t* woT = (half_t*)(ws + 23 * MB);  // 2MB
  half_t* qbuf = (half_t*)(ws + 25 * MB); // 8MB
  half_t* kbuf = (half_t*)(ws + 33 * MB); // 8MB
  half_t* vTg = (half_t*)(ws + 41 * MB);  // 8MB ([bh][d][s])
  half_t* ctx = xq;                       // alias (xq dead after proj phase)

  hipLaunchKernelGGL(prep, dim3(4112), dim3(256), 0, stream,
                     query, key_value, Wq, Wkv, Wo, xq, xkv, wqT, wkvT, woT,
                     tok, tok16, maskw, ctrs);
  hipLaunchKernelGGL(fused, dim3(512), dim3(512), 49152, stream,
                     xq, xkv, wqT, wkvT, bq, bkv, qbuf, kbuf, vTg,
                     maskw, tok, tok16, ctx, woT, bo, (float*)d_out, ctrs);
}

// Round 7
// 219.867 us; speedup vs baseline: 3.8229x; 3.3421x over previous
//
#include <hip/hip_runtime.h>
#include <stdint.h>

typedef _Float16 half_t;
typedef __attribute__((ext_vector_type(8))) _Float16 half8;
typedef __attribute__((ext_vector_type(4))) _Float16 half4;
typedef __attribute__((ext_vector_type(4))) float floatx4;

#define SEQ 2048
#define NH 16
#define HD 64

#define MFMA16(a, b, c) __builtin_amdgcn_mfma_f32_16x16x16f16(a, b, c, 0, 0, 0)
#define MFMA32K(a, b, c) __builtin_amdgcn_mfma_f32_16x16x32_f16(a, b, c, 0, 0, 0)

// SCALE * log2(e): scores exit QK in log2 domain -> raw v_exp_f32
#define QSCALE 0.1803368801111306f

// ---------------- prep: casts + weight transposes + mask tables -------------
__global__ __launch_bounds__(256) void prep(
    const float* __restrict__ query, const float* __restrict__ key_value,
    const float* __restrict__ Wq, const float* __restrict__ Wkv,
    const float* __restrict__ Wo, half_t* __restrict__ xq,
    half_t* __restrict__ xkv, half_t* __restrict__ wqT,
    half_t* __restrict__ wkvT, half_t* __restrict__ woT,
    uint8_t* __restrict__ tok, uint8_t* __restrict__ tok16,
    uint64_t* __restrict__ maskw) {
  int bx = blockIdx.x, tid = threadIdx.x;
  if (bx < 2048) {  // fp32 -> f16 casts, 4096 elements per block
    const float* s; half_t* d; int base;
    if (bx < 1024) { s = query; d = xq; base = bx * 4096; }
    else { s = key_value; d = xkv; base = (bx - 1024) * 4096; }
#pragma unroll
    for (int u = 0; u < 4; ++u) {
      int i = base + u * 1024 + tid * 4;
      floatx4 v = *(const floatx4*)(s + i);
      half4 h;
      h[0] = (half_t)v[0]; h[1] = (half_t)v[1];
      h[2] = (half_t)v[2]; h[3] = (half_t)v[3];
      *(half4*)(d + i) = h;
    }
    return;
  }
  if (bx < 4096) {  // weight transpose+cast, 2 tiles per block
    __shared__ float tile[32][33];
    int tx = tid & 31, ty = tid >> 5;
    const int K = 1024;
#pragma unroll
    for (int u = 0; u < 2; ++u) {
      int t = (bx - 2048) * 2 + u;
      const float* W; half_t* Wt; int N, nt, kt;
      if (t < 1024) { W = Wq; Wt = wqT; N = 1024; nt = t & 31; kt = t >> 5; }
      else if (t < 3072) { int t2 = t - 1024; W = Wkv; Wt = wkvT; N = 2048; nt = t2 & 63; kt = t2 >> 6; }
      else { int t2 = t - 3072; W = Wo; Wt = woT; N = 1024; nt = t2 & 31; kt = t2 >> 5; }
      int n0 = nt * 32, k0 = kt * 32;
#pragma unroll
      for (int i = 0; i < 4; ++i)
        tile[ty + i * 8][tx] = W[(size_t)(k0 + ty + i * 8) * N + n0 + tx];
      __syncthreads();
#pragma unroll
      for (int i = 0; i < 4; ++i)
        Wt[(size_t)(n0 + ty + i * 8) * K + k0 + tx] = (half_t)tile[tx][ty + i * 8];
      __syncthreads();
    }
    return;
  }
  // mask tables
  __shared__ uint8_t slut[2048];
  int ib = bx - 4096;
  for (int d = tid; d < 2048; d += 256) {
    int x = d;
    bool ok = true;
    for (int it = 0; it < 7; ++it) { ok &= ((x % 3) != 1); x /= 3; }
    ok &= (x == 0);
    slut[d] = (ok || d <= 64) ? 1 : 0;
  }
  __syncthreads();
  if (ib == 0) {
    if (tid < 64) {  // 64-gran tile activity
      int delta = tid - 32;
      int lo = delta * 64 - 63, hi = delta * 64 + 63;
      uint8_t any = 0;
      for (int x = lo; x <= hi; ++x) {
        int a = x < 0 ? -x : x;
        if (a < 2048) any |= slut[a];
      }
      tok[tid] = any;
    }
    {  // 16-gran subtile activity
      int d16 = tid - 128;
      int ctr = d16 * 16;
      uint8_t any = 0;
      for (int x = ctr - 15; x <= ctr + 15; ++x) {
        int a = x < 0 ? -x : x;
        if (a < 2048) any |= slut[a];
      }
      tok16[tid] = any;
    }
  }
  int g = ib * 256 + tid;  // 0..4095
  int tt = g - 2048;
  uint64_t w = 0;
  for (int jj = 0; jj < 64; ++jj) {
    int d = tt - jj; d = d < 0 ? -d : d;
    if (d < 2048 && slut[d]) w |= (1ull << jj);
  }
  maskw[g] = w;
}

// ---------------- async global->LDS 16B -------------------------------------
__device__ __forceinline__ void cp16(half_t* lds, const half_t* g) {
  __builtin_amdgcn_global_load_lds(
      (const __attribute__((address_space(1))) uint32_t*)g,
      (__attribute__((address_space(3))) uint32_t*)lds, 16, 0, 0);
}

// ---------------- fused q+kv projection GEMM, coalesced epilogue ------------
// r7: q/k epilogue ep stride 128 -> 132. With 128 (word idx 64*ml) the wave's
// 4 quads sit at ml,ml+4,ml+8,ml+12 -> 256 words apart -> SAME bank -> 4-way
// conflict on every scalar b16 write (this was the constant 3.5M
// SQ_LDS_BANK_CONFLICT, not the fragment reads). 66 words/row puts quads at
// bank offsets 0/8/16/24 -> conflict-free. 128*132*2B = 33792 <= 34816 dyn.
__global__ __launch_bounds__(256) void gemm_qkv(
    const half_t* __restrict__ xq, const half_t* __restrict__ xkv,
    const half_t* __restrict__ wqT, const half_t* __restrict__ wkvT,
    const float* __restrict__ bq, const float* __restrict__ bkv,
    half_t* __restrict__ qout, half_t* __restrict__ kout,
    half_t* __restrict__ vTout) {
  extern __shared__ char smemraw[];
  half_t* As = (half_t*)smemraw;  // 2 x 128x32
  half_t* Bs = As + 8192;         // 2 x 128x32
  const int K = 1024;
  bool isq = blockIdx.y < 8;
  const half_t* A = isq ? xq : xkv;
  const half_t* Bt = isq ? wqT : wkvT;
  const float* bias = isq ? bq : bkv;
  int n0 = (isq ? blockIdx.y : (blockIdx.y - 8)) * 128;
  int m0 = blockIdx.x * 128;

  int tid = threadIdx.x;
  int wave = tid >> 6, lane = tid & 63;
  int c = lane & 15, quad = lane >> 4;
  int wm = (wave >> 1) * 64, wn = (wave & 1) * 64;

  floatx4 acc[4][4] = {};
  int arow = tid >> 2;
  int akc = ((tid & 3) ^ (arow & 3)) * 8;  // pre-swizzled source chunk
  int csw = c & 3;                         // read-side XOR (row&3 == c&3)

  cp16(&As[wave * 512], A + (size_t)(m0 + arow) * K + akc);
  cp16(&As[2048 + wave * 512], A + (size_t)(m0 + 64 + arow) * K + akc);
  cp16(&Bs[wave * 512], Bt + (size_t)(n0 + arow) * K + akc);
  cp16(&Bs[2048 + wave * 512], Bt + (size_t)(n0 + 64 + arow) * K + akc);

  for (int kt = 0; kt < 32; ++kt) {
    __syncthreads();
    if (kt + 1 < 32) {
      int k0 = (kt + 1) * 32;
      int b = (kt + 1) & 1;
      cp16(&As[b * 4096 + wave * 512], A + (size_t)(m0 + arow) * K + k0 + akc);
      cp16(&As[b * 4096 + 2048 + wave * 512], A + (size_t)(m0 + 64 + arow) * K + k0 + akc);
      cp16(&Bs[b * 4096 + wave * 512], Bt + (size_t)(n0 + arow) * K + k0 + akc);
      cp16(&Bs[b * 4096 + 2048 + wave * 512], Bt + (size_t)(n0 + 64 + arow) * K + k0 + akc);
    }
    int b = kt & 1;
    half8 af[4], bf[4];
#pragma unroll
    for (int mt = 0; mt < 4; ++mt)
      af[mt] = *(const half8*)&As[b * 4096 + (wm + mt * 16 + c) * 32 + ((quad ^ csw) * 8)];
#pragma unroll
    for (int nt = 0; nt < 4; ++nt)
      bf[nt] = *(const half8*)&Bs[b * 4096 + (wn + nt * 16 + c) * 32 + ((quad ^ csw) * 8)];
#pragma unroll
    for (int mt = 0; mt < 4; ++mt)
#pragma unroll
      for (int nt = 0; nt < 4; ++nt)
        acc[mt][nt] = MFMA32K(af[mt], bf[nt], acc[mt][nt]);
  }

  __syncthreads();
  half_t* ep = (half_t*)smemraw;
  int bb = m0 >> 11, sbase = m0 & 2047;
  bool isv = (!isq) && (n0 >= 1024);

  if (!isv) {  // q or k: ep[m][n] stride 132 (conflict-free) -> [bh][s][d]
#pragma unroll
    for (int nt = 0; nt < 4; ++nt) {
      int nl = wn + nt * 16 + c;
      float bv = bias[n0 + nl];
#pragma unroll
      for (int mt = 0; mt < 4; ++mt)
#pragma unroll
        for (int r = 0; r < 4; ++r) {
          int ml = wm + mt * 16 + quad * 4 + r;
          float v = acc[mt][nt][r] + bv;
          if (isq) v *= QSCALE;
          ep[ml * 132 + nl] = (half_t)v;
        }
    }
    __syncthreads();
    half_t* outp = isq ? qout : kout;
#pragma unroll
    for (int rd = 0; rd < 8; ++rd) {
      int id = rd * 256 + tid;  // 2048 chunks of 16B
      int ml = id >> 4, ch = id & 15;
      int ng = n0 + ch * 8;
      int h = ng >> 6, d0 = ng & 63;
      half8 v = *(const half8*)&ep[ml * 132 + ch * 8];
      *(half8*)(outp + ((size_t)(bb * 16 + h) * SEQ + sbase + ml) * 64 + d0) = v;
    }
  } else {  // v: ep[n][m] stride 136 -> [bh][d][s]
#pragma unroll
    for (int nt = 0; nt < 4; ++nt) {
      int nl = wn + nt * 16 + c;
      float bv = bias[n0 + nl];
#pragma unroll
      for (int mt = 0; mt < 4; ++mt) {
        int ml = wm + mt * 16 + quad * 4;
        half4 hv;
#pragma unroll
        for (int r = 0; r < 4; ++r) hv[r] = (half_t)(acc[mt][nt][r] + bv);
        *(half4*)&ep[nl * 136 + ml] = hv;
      }
    }
    __syncthreads();
#pragma unroll
    for (int rd = 0; rd < 8; ++rd) {
      int id = rd * 256 + tid;
      int nl = id >> 4, mc = id & 15;
      int ng = n0 + nl;
      int h = (ng >> 6) & 15, d = ng & 63;
      half8 v = *(const half8*)&ep[nl * 136 + mc * 8];
      *(half8*)(vTout + ((size_t)(bb * 16 + h) * 64 + d) * SEQ + sbase + mc * 8) = v;
    }
  }
}

// ---------------- out-projection GEMM: 128x128 tiles, 256 blocks = 1/CU -----
__global__ __launch_bounds__(256) void gemm_out(
    const half_t* __restrict__ A, const half_t* __restrict__ Bt,
    const float* __restrict__ bias, float* __restrict__ outf) {
  __shared__ half_t As[2][128 * 32];
  __shared__ half_t Bs[2][128 * 32];
  const int K = 1024;
  int tid = threadIdx.x;
  int wave = tid >> 6, lane = tid & 63;
  int c = lane & 15, quad = lane >> 4;
  int wm = (wave >> 1) * 64, wn = (wave & 1) * 64;
  int m0 = blockIdx.x * 128, n0 = blockIdx.y * 128;

  floatx4 acc[4][4] = {};
  int arow = tid >> 2;
  int akc = ((tid & 3) ^ (arow & 3)) * 8;  // pre-swizzled source chunk
  int csw = c & 3;

  cp16(&As[0][wave * 512], A + (size_t)(m0 + arow) * K + akc);
  cp16(&As[0][2048 + wave * 512], A + (size_t)(m0 + 64 + arow) * K + akc);
  cp16(&Bs[0][wave * 512], Bt + (size_t)(n0 + arow) * K + akc);
  cp16(&Bs[0][2048 + wave * 512], Bt + (size_t)(n0 + 64 + arow) * K + akc);

  for (int kt = 0; kt < 32; ++kt) {
    __syncthreads();
    if (kt + 1 < 32) {
      int k0 = (kt + 1) * 32;
      int b = (kt + 1) & 1;
      cp16(&As[b][wave * 512], A + (size_t)(m0 + arow) * K + k0 + akc);
      cp16(&As[b][2048 + wave * 512], A + (size_t)(m0 + 64 + arow) * K + k0 + akc);
      cp16(&Bs[b][wave * 512], Bt + (size_t)(n0 + arow) * K + k0 + akc);
      cp16(&Bs[b][2048 + wave * 512], Bt + (size_t)(n0 + 64 + arow) * K + k0 + akc);
    }
    int b = kt & 1;
    half8 af[4], bf[4];
#pragma unroll
    for (int mt = 0; mt < 4; ++mt)
      af[mt] = *(const half8*)&As[b][(wm + mt * 16 + c) * 32 + ((quad ^ csw) * 8)];
#pragma unroll
    for (int nt = 0; nt < 4; ++nt)
      bf[nt] = *(const half8*)&Bs[b][(wn + nt * 16 + c) * 32 + ((quad ^ csw) * 8)];
#pragma unroll
    for (int mt = 0; mt < 4; ++mt)
#pragma unroll
      for (int nt = 0; nt < 4; ++nt)
        acc[mt][nt] = MFMA32K(af[mt], bf[nt], acc[mt][nt]);
  }

#pragma unroll
  for (int nt = 0; nt < 4; ++nt) {
    int n = n0 + wn + nt * 16 + c;
    float bv = bias[n];
#pragma unroll
    for (int mt = 0; mt < 4; ++mt)
#pragma unroll
      for (int r = 0; r < 4; ++r) {
        int m = m0 + wm + mt * 16 + quad * 4 + r;
        outf[(size_t)m * 1024 + n] = acc[mt][nt][r] + bv;
      }
  }
}

// ---------------- masked flash attention ------------------------------------
// r4 structure verbatim (best measured) + T5 setprio around MFMA clusters
// (2 independent blocks/CU give scheduler phase diversity; m191: +4-7% attn).
__global__ __launch_bounds__(512) void attn_kernel(
    const half_t* __restrict__ qb, const half_t* __restrict__ kb,
    const half_t* __restrict__ vTg, half_t* __restrict__ ctx,
    const uint64_t* __restrict__ maskw, const uint8_t* __restrict__ tok,
    const uint8_t* __restrict__ tok16g) {
  __shared__ half_t kT[64 * 64];
  __shared__ half_t vT[64 * 64];
  __shared__ half_t ot[128 * 72];
  __shared__ int list[34];
  __shared__ uint8_t tok16s[256];

  int tid = threadIdx.x, wave = tid >> 6, lane = tid & 63;
  int c = lane & 15, q = lane >> 4;
  int id = blockIdx.x;
  int bh = (id & 7) * 4 + ((id >> 3) & 3);  // XCD-major: bh fixed per XCD
  int it128 = id >> 5;
  int i0 = it128 << 7;
  const half_t* qbase = qb + (size_t)bh * SEQ * HD;
  const half_t* kg = kb + (size_t)bh * SEQ * HD;
  const half_t* vg = vTg + (size_t)bh * HD * SEQ;

  if (tid < 256) tok16s[tid] = tok16g[tid];
  if (wave == 0) {
    int jt = lane;
    int base = i0 >> 6;
    bool act = (jt < 32) &&
               (tok[(jt - base) + 32] | tok[(jt - base - 1) + 32]);
    unsigned long long bal = __ballot(act);
    if (act) {
      int pre = __popcll(bal & ((1ull << jt) - 1));
      list[1 + pre] = jt << 6;
    }
    if (lane == 0) list[0] = __popcll(bal);
  }

  int i_row = i0 + wave * 16 + c;
  int it16 = (i0 >> 4) + wave;
  half8 qf0 = *(const half8*)(qbase + (size_t)i_row * 64 + q * 8);
  half8 qf1 = *(const half8*)(qbase + (size_t)i_row * 64 + 32 + q * 8);

  floatx4 oacc[4] = {};
  floatx4 lacc = {};
  half4 ones;
  ones[0] = (half_t)1.f; ones[1] = (half_t)1.f;
  ones[2] = (half_t)1.f; ones[3] = (half_t)1.f;

  int srow = tid >> 3;      // 0..63
  int sch = tid & 7;        // 0..7
  int ssw = srow & 7;

  __syncthreads();  // list + tok16s ready
  int nact = list[0];
  int j0 = list[1];

  half8 kr = *(const half8*)(kg + (size_t)(j0 + srow) * 64 + sch * 8);
  half8 vr = *(const half8*)(vg + (size_t)srow * SEQ + j0 + sch * 8);
  uint64_t wcur = maskw[(i_row - j0) + 2048];

  for (int ti = 0; ti < nact; ++ti) {
    int bidx = (j0 >> 4) - it16 + 128;
    __syncthreads();  // A: previous compute done
    *(half8*)&kT[srow * 64 + ((sch ^ ssw) * 8)] = kr;
    *(half8*)&vT[srow * 64 + ((sch ^ ssw) * 8)] = vr;
    int j0n = (ti + 1 < nact) ? list[2 + ti] : j0;
    __syncthreads();  // B: ds_writes visible

    // T14: issue next-tile loads AFTER the barrier
    uint64_t wnext = wcur;
    if (ti + 1 < nact) {
      kr = *(const half8*)(kg + (size_t)(j0n + srow) * 64 + sch * 8);
      vr = *(const half8*)(vg + (size_t)srow * SEQ + j0n + sch * 8);
      wnext = maskw[(i_row - j0n) + 2048];
    }

    uint32_t wlo = (uint32_t)(wcur >> (4 * q));
    uint32_t whi = (uint32_t)(wcur >> (32 + 4 * q));
#pragma unroll
    for (int jt = 0; jt < 4; ++jt) {
      if (!tok16s[bidx + jt]) continue;  // wave-uniform subtile skip
      int row = jt * 16 + c;
      int sw = c & 7;
      half8 a0 = *(const half8*)&kT[row * 64 + ((q ^ sw) * 8)];
      half8 a1 = *(const half8*)&kT[row * 64 + (((4 + q) ^ sw) * 8)];
      floatx4 t = {};
      __builtin_amdgcn_s_setprio(1);
      t = MFMA32K(a0, qf0, t);
      t = MFMA32K(a1, qf1, t);
      __builtin_amdgcn_s_setprio(0);
      uint32_t ww = (jt < 2) ? wlo : whi;
#pragma unroll
      for (int r = 0; r < 4; ++r) {
        float p = __builtin_exp2f(t[r]);
        int bitpos = 16 * (jt & 1) + r;
        uint32_t msk = (uint32_t)(((int)(ww << (31 - bitpos))) >> 31);
        t[r] = __uint_as_float(__float_as_uint(p) & msk);
      }
      auto lo = __builtin_amdgcn_cvt_pkrtz(t[0], t[1]);
      auto hi = __builtin_amdgcn_cvt_pkrtz(t[2], t[3]);
      half4 pb;
      pb[0] = lo[0]; pb[1] = lo[1]; pb[2] = hi[0]; pb[3] = hi[1];
      __builtin_amdgcn_s_setprio(1);
      lacc = MFMA16(ones, pb, lacc);
#pragma unroll
      for (int mt = 0; mt < 4; ++mt) {
        int drow = mt * 16 + c;
        int ch = 2 * jt + (q >> 1);
        half4 a = *(const half4*)&vT[drow * 64 + ((ch ^ sw) * 8) + (q & 1) * 4];
        oacc[mt] = MFMA16(a, pb, oacc[mt]);
      }
      __builtin_amdgcn_s_setprio(0);
    }
    wcur = wnext;
    j0 = j0n;
  }

  // epilogue: normalize, transpose via LDS, coalesced ctx write
  float inv_l = 1.0f / lacc[0];
#pragma unroll
  for (int mt = 0; mt < 4; ++mt)
#pragma unroll
    for (int r = 0; r < 4; ++r)
      ot[(wave * 16 + c) * 72 + mt * 16 + 4 * q + r] = (half_t)(oacc[mt][r] * inv_l);
  __syncthreads();
  {
    int row = tid >> 2, chq = tid & 3;  // 128 rows x 4 chunk-pairs
    int b = bh >> 4, h = bh & 15;
    size_t base = (((size_t)(b * SEQ + i0 + row) * NH) + h) * 64 + chq * 16;
    half8 v0 = *(const half8*)&ot[row * 72 + chq * 16];
    half8 v1 = *(const half8*)&ot[row * 72 + chq * 16 + 8];
    *(half8*)(ctx + base) = v0;
    *(half8*)(ctx + base + 8) = v1;
  }
}

// ---------------- launch -----------------------------------------------------
extern "C" void kernel_launch(void* const* d_in, const int* in_sizes, int n_in,
                              void* d_out, int out_size, void* d_ws, size_t ws_size,
                              hipStream_t stream) {
  const float* query = (const float*)d_in[0];
  const float* key_value = (const float*)d_in[1];
  const float* Wq = (const float*)d_in[2];
  const float* bq = (const float*)d_in[3];
  const float* Wkv = (const float*)d_in[4];
  const float* bkv = (const float*)d_in[5];
  const float* Wo = (const float*)d_in[6];
  const float* bo = (const float*)d_in[7];

  char* ws = (char*)d_ws;
  uint8_t* tok = (uint8_t*)ws;               // 64
  uint8_t* tok16 = (uint8_t*)(ws + 1024);    // 256
  uint64_t* maskw = (uint64_t*)(ws + 4096);  // 32KB
  const size_t MB = 1ull << 20;
  half_t* xq = (half_t*)(ws + 1 * MB);    // 8MB; reused as ctx after qkv gemm
  half_t* xkv = (half_t*)(ws + 9 * MB);   // 8MB
  half_t* wqT = (half_t*)(ws + 17 * MB);  // 2MB
  half_t* wkvT = (half_t*)(ws + 19 * MB); // 4MB
  half_t* woT = (half_t*)(ws + 23 * MB);  // 2MB
  half_t* qbuf = (half_t*)(ws + 25 * MB); // 8MB
  half_t* kbuf = (half_t*)(ws + 33 * MB); // 8MB
  half_t* vTg = (half_t*)(ws + 41 * MB);  // 8MB ([bh][d][s])
  half_t* ctx = xq;                       // alias (xq dead after proj)

  hipLaunchKernelGGL(prep, dim3(4112), dim3(256), 0, stream,
                     query, key_value, Wq, Wkv, Wo, xq, xkv, wqT, wkvT, woT,
                     tok, tok16, maskw);
  hipLaunchKernelGGL(gemm_qkv, dim3(32, 24), dim3(256), 34816, stream,
                     xq, xkv, wqT, wkvT, bq, bkv, qbuf, kbuf, vTg);
  hipLaunchKernelGGL(attn_kernel, dim3(512), dim3(512), 0, stream,
                     qbuf, kbuf, vTg, ctx, maskw, tok, tok16);
  hipLaunchKernelGGL(gemm_out, dim3(32, 8), dim3(256), 0, stream,
                     ctx, woT, bo, (float*)d_out);
}

// Round 8
// 210.534 us; speedup vs baseline: 3.9924x; 1.0443x over previous
//
#include <hip/hip_runtime.h>
#include <stdint.h>

typedef _Float16 half_t;
typedef __attribute__((ext_vector_type(8))) _Float16 half8;
typedef __attribute__((ext_vector_type(4))) _Float16 half4;
typedef __attribute__((ext_vector_type(4))) float floatx4;

#define SEQ 2048
#define NH 16
#define HD 64

#define MFMA16(a, b, c) __builtin_amdgcn_mfma_f32_16x16x16f16(a, b, c, 0, 0, 0)
#define MFMA32K(a, b, c) __builtin_amdgcn_mfma_f32_16x16x32_f16(a, b, c, 0, 0, 0)

// SCALE * log2(e): scores exit QK in log2 domain -> raw v_exp_f32
#define QSCALE 0.1803368801111306f

// ---------------- prep: casts + weight transposes + mask tables -------------
__global__ __launch_bounds__(256) void prep(
    const float* __restrict__ query, const float* __restrict__ key_value,
    const float* __restrict__ Wq, const float* __restrict__ Wkv,
    const float* __restrict__ Wo, half_t* __restrict__ xq,
    half_t* __restrict__ xkv, half_t* __restrict__ wqT,
    half_t* __restrict__ wkvT, half_t* __restrict__ woT,
    uint8_t* __restrict__ tok, uint8_t* __restrict__ tok16,
    uint64_t* __restrict__ maskw) {
  int bx = blockIdx.x, tid = threadIdx.x;
  if (bx < 2048) {  // fp32 -> f16 casts, 4096 elements per block
    const float* s; half_t* d; int base;
    if (bx < 1024) { s = query; d = xq; base = bx * 4096; }
    else { s = key_value; d = xkv; base = (bx - 1024) * 4096; }
#pragma unroll
    for (int u = 0; u < 4; ++u) {
      int i = base + u * 1024 + tid * 4;
      floatx4 v = *(const floatx4*)(s + i);
      half4 h;
      h[0] = (half_t)v[0]; h[1] = (half_t)v[1];
      h[2] = (half_t)v[2]; h[3] = (half_t)v[3];
      *(half4*)(d + i) = h;
    }
    return;
  }
  if (bx < 4096) {  // weight transpose+cast, 2 tiles per block
    __shared__ float tile[32][33];
    int tx = tid & 31, ty = tid >> 5;
    const int K = 1024;
#pragma unroll
    for (int u = 0; u < 2; ++u) {
      int t = (bx - 2048) * 2 + u;
      const float* W; half_t* Wt; int N, nt, kt;
      if (t < 1024) { W = Wq; Wt = wqT; N = 1024; nt = t & 31; kt = t >> 5; }
      else if (t < 3072) { int t2 = t - 1024; W = Wkv; Wt = wkvT; N = 2048; nt = t2 & 63; kt = t2 >> 6; }
      else { int t2 = t - 3072; W = Wo; Wt = woT; N = 1024; nt = t2 & 31; kt = t2 >> 5; }
      int n0 = nt * 32, k0 = kt * 32;
#pragma unroll
      for (int i = 0; i < 4; ++i)
        tile[ty + i * 8][tx] = W[(size_t)(k0 + ty + i * 8) * N + n0 + tx];
      __syncthreads();
#pragma unroll
      for (int i = 0; i < 4; ++i)
        Wt[(size_t)(n0 + ty + i * 8) * K + k0 + tx] = (half_t)tile[tx][ty + i * 8];
      __syncthreads();
    }
    return;
  }
  // mask tables
  __shared__ uint8_t slut[2048];
  int ib = bx - 4096;
  for (int d = tid; d < 2048; d += 256) {
    int x = d;
    bool ok = true;
    for (int it = 0; it < 7; ++it) { ok &= ((x % 3) != 1); x /= 3; }
    ok &= (x == 0);
    slut[d] = (ok || d <= 64) ? 1 : 0;
  }
  __syncthreads();
  if (ib == 0) {
    if (tid < 64) {  // 64-gran tile activity
      int delta = tid - 32;
      int lo = delta * 64 - 63, hi = delta * 64 + 63;
      uint8_t any = 0;
      for (int x = lo; x <= hi; ++x) {
        int a = x < 0 ? -x : x;
        if (a < 2048) any |= slut[a];
      }
      tok[tid] = any;
    }
    {  // 16-gran subtile activity
      int d16 = tid - 128;
      int ctr = d16 * 16;
      uint8_t any = 0;
      for (int x = ctr - 15; x <= ctr + 15; ++x) {
        int a = x < 0 ? -x : x;
        if (a < 2048) any |= slut[a];
      }
      tok16[tid] = any;
    }
  }
  int g = ib * 256 + tid;  // 0..4095
  int tt = g - 2048;
  uint64_t w = 0;
  for (int jj = 0; jj < 64; ++jj) {
    int d = tt - jj; d = d < 0 ? -d : d;
    if (d < 2048 && slut[d]) w |= (1ull << jj);
  }
  maskw[g] = w;
}

// ---------------- async global->LDS 16B -------------------------------------
__device__ __forceinline__ void cp16(half_t* lds, const half_t* g) {
  __builtin_amdgcn_global_load_lds(
      (const __attribute__((address_space(1))) uint32_t*)g,
      (__attribute__((address_space(3))) uint32_t*)lds, 16, 0, 0);
}

// ---------------- fused q+kv projection GEMM --------------------------------
// r8 (T4, m201-template pattern in plain HIP): triple-buffered LDS, prefetch
// depth 2, raw s_barrier + COUNTED s_waitcnt vmcnt(4) instead of
// __syncthreads' vmcnt(0) drain. Each wave keeps its 4 next-tile
// global_load_lds in flight across the barrier -> load latency spans a full
// K-step instead of stalling every iteration (~200cyc/iter was dead).
// Tile kt+2 is issued AFTER the barrier so its DMA cannot land in a buffer a
// lagging wave still reads (3-buffer rotation = one iteration of separation).
__global__ __launch_bounds__(256) void gemm_qkv(
    const half_t* __restrict__ xq, const half_t* __restrict__ xkv,
    const half_t* __restrict__ wqT, const half_t* __restrict__ wkvT,
    const float* __restrict__ bq, const float* __restrict__ bkv,
    half_t* __restrict__ qout, half_t* __restrict__ kout,
    half_t* __restrict__ vTout) {
  extern __shared__ char smemraw[];
  half_t* As = (half_t*)smemraw;  // 3 x 128x32
  half_t* Bs = As + 12288;        // 3 x 128x32
  const int K = 1024;
  bool isq = blockIdx.y < 8;
  const half_t* A = isq ? xq : xkv;
  const half_t* Bt = isq ? wqT : wkvT;
  const float* bias = isq ? bq : bkv;
  int n0 = (isq ? blockIdx.y : (blockIdx.y - 8)) * 128;
  int m0 = blockIdx.x * 128;

  int tid = threadIdx.x;
  int wave = tid >> 6, lane = tid & 63;
  int c = lane & 15, quad = lane >> 4;
  int wm = (wave >> 1) * 64, wn = (wave & 1) * 64;

  floatx4 acc[4][4] = {};
  int arow = tid >> 2;
  int akc = ((tid & 3) ^ (arow & 3)) * 8;  // pre-swizzled source chunk
  int csw = c & 3;                         // read-side XOR (row&3 == c&3)

#define QKV_ISSUE(kt2)                                                        \
  {                                                                           \
    int s_ = (kt2) % 3;                                                       \
    int k0_ = (kt2) * 32;                                                     \
    cp16(&As[s_ * 4096 + wave * 512], A + (size_t)(m0 + arow) * K + k0_ + akc);          \
    cp16(&As[s_ * 4096 + 2048 + wave * 512], A + (size_t)(m0 + 64 + arow) * K + k0_ + akc); \
    cp16(&Bs[s_ * 4096 + wave * 512], Bt + (size_t)(n0 + arow) * K + k0_ + akc);         \
    cp16(&Bs[s_ * 4096 + 2048 + wave * 512], Bt + (size_t)(n0 + 64 + arow) * K + k0_ + akc); \
  }

  QKV_ISSUE(0)
  QKV_ISSUE(1)

  for (int kt = 0; kt < 32; ++kt) {
    // wait for tile kt's 4 loads (oldest in FIFO); tile kt+1's 4 stay in flight
    if (kt < 31) {
      asm volatile("s_waitcnt vmcnt(4)" ::: "memory");
    } else {
      asm volatile("s_waitcnt vmcnt(0)" ::: "memory");
    }
    __builtin_amdgcn_s_barrier();
    if (kt + 2 < 32) QKV_ISSUE(kt + 2)
    int b = kt % 3;
    half8 af[4], bf[4];
#pragma unroll
    for (int mt = 0; mt < 4; ++mt)
      af[mt] = *(const half8*)&As[b * 4096 + (wm + mt * 16 + c) * 32 + ((quad ^ csw) * 8)];
#pragma unroll
    for (int nt = 0; nt < 4; ++nt)
      bf[nt] = *(const half8*)&Bs[b * 4096 + (wn + nt * 16 + c) * 32 + ((quad ^ csw) * 8)];
#pragma unroll
    for (int mt = 0; mt < 4; ++mt)
#pragma unroll
      for (int nt = 0; nt < 4; ++nt)
        acc[mt][nt] = MFMA32K(af[mt], bf[nt], acc[mt][nt]);
  }
#undef QKV_ISSUE

  __syncthreads();
  half_t* ep = (half_t*)smemraw;
  int bb = m0 >> 11, sbase = m0 & 2047;
  bool isv = (!isq) && (n0 >= 1024);

  if (!isv) {  // q or k: ep[m][n] stride 132 (conflict-free) -> [bh][s][d]
#pragma unroll
    for (int nt = 0; nt < 4; ++nt) {
      int nl = wn + nt * 16 + c;
      float bv = bias[n0 + nl];
#pragma unroll
      for (int mt = 0; mt < 4; ++mt)
#pragma unroll
        for (int r = 0; r < 4; ++r) {
          int ml = wm + mt * 16 + quad * 4 + r;
          float v = acc[mt][nt][r] + bv;
          if (isq) v *= QSCALE;
          ep[ml * 132 + nl] = (half_t)v;
        }
    }
    __syncthreads();
    half_t* outp = isq ? qout : kout;
#pragma unroll
    for (int rd = 0; rd < 8; ++rd) {
      int id = rd * 256 + tid;  // 2048 chunks of 16B
      int ml = id >> 4, ch = id & 15;
      int ng = n0 + ch * 8;
      int h = ng >> 6, d0 = ng & 63;
      half8 v = *(const half8*)&ep[ml * 132 + ch * 8];
      *(half8*)(outp + ((size_t)(bb * 16 + h) * SEQ + sbase + ml) * 64 + d0) = v;
    }
  } else {  // v: ep[n][m] stride 136 -> [bh][d][s]
#pragma unroll
    for (int nt = 0; nt < 4; ++nt) {
      int nl = wn + nt * 16 + c;
      float bv = bias[n0 + nl];
#pragma unroll
      for (int mt = 0; mt < 4; ++mt) {
        int ml = wm + mt * 16 + quad * 4;
        half4 hv;
#pragma unroll
        for (int r = 0; r < 4; ++r) hv[r] = (half_t)(acc[mt][nt][r] + bv);
        *(half4*)&ep[nl * 136 + ml] = hv;
      }
    }
    __syncthreads();
#pragma unroll
    for (int rd = 0; rd < 8; ++rd) {
      int id = rd * 256 + tid;
      int nl = id >> 4, mc = id & 15;
      int ng = n0 + nl;
      int h = (ng >> 6) & 15, d = ng & 63;
      half8 v = *(const half8*)&ep[nl * 136 + mc * 8];
      *(half8*)(vTout + ((size_t)(bb * 16 + h) * 64 + d) * SEQ + sbase + mc * 8) = v;
    }
  }
}

// ---------------- out-projection GEMM: 128x64 tiles, fp32 out (r4) ----------
__global__ __launch_bounds__(256) void gemm_out(
    const half_t* __restrict__ A, const half_t* __restrict__ Bt,
    const float* __restrict__ bias, float* __restrict__ outf) {
  __shared__ half_t As[2][128 * 32];
  __shared__ half_t Bs[2][64 * 32];
  const int K = 1024;
  int tid = threadIdx.x;
  int wave = tid >> 6, lane = tid & 63;
  int c = lane & 15, quad = lane >> 4;
  int wm = (wave >> 1) * 64, wn = (wave & 1) * 32;
  int m0 = blockIdx.x * 128, n0 = blockIdx.y * 64;

  floatx4 acc[4][2] = {};
  int arow = tid >> 2;
  int akc = ((tid & 3) ^ (arow & 3)) * 8;  // pre-swizzled source chunk
  int csw = c & 3;

  cp16(&As[0][wave * 512], A + (size_t)(m0 + arow) * K + akc);
  cp16(&As[0][2048 + wave * 512], A + (size_t)(m0 + 64 + arow) * K + akc);
  cp16(&Bs[0][wave * 512], Bt + (size_t)(n0 + arow) * K + akc);

  for (int kt = 0; kt < 32; ++kt) {
    __syncthreads();
    if (kt + 1 < 32) {
      int k0 = (kt + 1) * 32;
      int b = (kt + 1) & 1;
      cp16(&As[b][wave * 512], A + (size_t)(m0 + arow) * K + k0 + akc);
      cp16(&As[b][2048 + wave * 512], A + (size_t)(m0 + 64 + arow) * K + k0 + akc);
      cp16(&Bs[b][wave * 512], Bt + (size_t)(n0 + arow) * K + k0 + akc);
    }
    int b = kt & 1;
    half8 af[4], bf[2];
#pragma unroll
    for (int mt = 0; mt < 4; ++mt)
      af[mt] = *(const half8*)&As[b][(wm + mt * 16 + c) * 32 + ((quad ^ csw) * 8)];
#pragma unroll
    for (int nt = 0; nt < 2; ++nt)
      bf[nt] = *(const half8*)&Bs[b][(wn + nt * 16 + c) * 32 + ((quad ^ csw) * 8)];
#pragma unroll
    for (int mt = 0; mt < 4; ++mt)
#pragma unroll
      for (int nt = 0; nt < 2; ++nt)
        acc[mt][nt] = MFMA32K(af[mt], bf[nt], acc[mt][nt]);
  }

#pragma unroll
  for (int nt = 0; nt < 2; ++nt) {
    int n = n0 + wn + nt * 16 + c;
    float bv = bias[n];
#pragma unroll
    for (int mt = 0; mt < 4; ++mt)
#pragma unroll
      for (int r = 0; r < 4; ++r) {
        int m = m0 + wm + mt * 16 + quad * 4 + r;
        outf[(size_t)m * 1024 + n] = acc[mt][nt][r] + bv;
      }
  }
}

// ---------------- masked flash attention (r4 verbatim) ----------------------
__global__ __launch_bounds__(512) void attn_kernel(
    const half_t* __restrict__ qb, const half_t* __restrict__ kb,
    const half_t* __restrict__ vTg, half_t* __restrict__ ctx,
    const uint64_t* __restrict__ maskw, const uint8_t* __restrict__ tok,
    const uint8_t* __restrict__ tok16g) {
  __shared__ half_t kT[64 * 64];
  __shared__ half_t vT[64 * 64];
  __shared__ half_t ot[128 * 72];
  __shared__ int list[34];
  __shared__ uint8_t tok16s[256];

  int tid = threadIdx.x, wave = tid >> 6, lane = tid & 63;
  int c = lane & 15, q = lane >> 4;
  int id = blockIdx.x;
  int bh = (id & 7) * 4 + ((id >> 3) & 3);  // XCD-major: bh fixed per XCD
  int it128 = id >> 5;
  int i0 = it128 << 7;
  const half_t* qbase = qb + (size_t)bh * SEQ * HD;
  const half_t* kg = kb + (size_t)bh * SEQ * HD;
  const half_t* vg = vTg + (size_t)bh * HD * SEQ;

  if (tid < 256) tok16s[tid] = tok16g[tid];
  if (wave == 0) {
    int jt = lane;
    int base = i0 >> 6;
    bool act = (jt < 32) &&
               (tok[(jt - base) + 32] | tok[(jt - base - 1) + 32]);
    unsigned long long bal = __ballot(act);
    if (act) {
      int pre = __popcll(bal & ((1ull << jt) - 1));
      list[1 + pre] = jt << 6;
    }
    if (lane == 0) list[0] = __popcll(bal);
  }

  int i_row = i0 + wave * 16 + c;
  int it16 = (i0 >> 4) + wave;
  half8 qf0 = *(const half8*)(qbase + (size_t)i_row * 64 + q * 8);
  half8 qf1 = *(const half8*)(qbase + (size_t)i_row * 64 + 32 + q * 8);

  floatx4 oacc[4] = {};
  floatx4 lacc = {};
  half4 ones;
  ones[0] = (half_t)1.f; ones[1] = (half_t)1.f;
  ones[2] = (half_t)1.f; ones[3] = (half_t)1.f;

  int srow = tid >> 3;      // 0..63
  int sch = tid & 7;        // 0..7
  int ssw = srow & 7;

  __syncthreads();  // list + tok16s ready
  int nact = list[0];
  int j0 = list[1];

  half8 kr = *(const half8*)(kg + (size_t)(j0 + srow) * 64 + sch * 8);
  half8 vr = *(const half8*)(vg + (size_t)srow * SEQ + j0 + sch * 8);
  uint64_t wcur = maskw[(i_row - j0) + 2048];

  for (int ti = 0; ti < nact; ++ti) {
    int bidx = (j0 >> 4) - it16 + 128;
    __syncthreads();  // A: previous compute done
    *(half8*)&kT[srow * 64 + ((sch ^ ssw) * 8)] = kr;
    *(half8*)&vT[srow * 64 + ((sch ^ ssw) * 8)] = vr;
    int j0n = (ti + 1 < nact) ? list[2 + ti] : j0;
    __syncthreads();  // B: ds_writes visible

    // T14: issue next-tile loads AFTER the barrier
    uint64_t wnext = wcur;
    if (ti + 1 < nact) {
      kr = *(const half8*)(kg + (size_t)(j0n + srow) * 64 + sch * 8);
      vr = *(const half8*)(vg + (size_t)srow * SEQ + j0n + sch * 8);
      wnext = maskw[(i_row - j0n) + 2048];
    }

    uint32_t wlo = (uint32_t)(wcur >> (4 * q));
    uint32_t whi = (uint32_t)(wcur >> (32 + 4 * q));
#pragma unroll
    for (int jt = 0; jt < 4; ++jt) {
      if (!tok16s[bidx + jt]) continue;  // wave-uniform subtile skip
      int row = jt * 16 + c;
      int sw = c & 7;
      half8 a0 = *(const half8*)&kT[row * 64 + ((q ^ sw) * 8)];
      half8 a1 = *(const half8*)&kT[row * 64 + (((4 + q) ^ sw) * 8)];
      floatx4 t = {};
      t = MFMA32K(a0, qf0, t);
      t = MFMA32K(a1, qf1, t);
      uint32_t ww = (jt < 2) ? wlo : whi;
#pragma unroll
      for (int r = 0; r < 4; ++r) {
        float p = __builtin_exp2f(t[r]);
        int bitpos = 16 * (jt & 1) + r;
        uint32_t msk = (uint32_t)(((int)(ww << (31 - bitpos))) >> 31);
        t[r] = __uint_as_float(__float_as_uint(p) & msk);
      }
      auto lo = __builtin_amdgcn_cvt_pkrtz(t[0], t[1]);
      auto hi = __builtin_amdgcn_cvt_pkrtz(t[2], t[3]);
      half4 pb;
      pb[0] = lo[0]; pb[1] = lo[1]; pb[2] = hi[0]; pb[3] = hi[1];
      lacc = MFMA16(ones, pb, lacc);
#pragma unroll
      for (int mt = 0; mt < 4; ++mt) {
        int drow = mt * 16 + c;
        int ch = 2 * jt + (q >> 1);
        half4 a = *(const half4*)&vT[drow * 64 + ((ch ^ sw) * 8) + (q & 1) * 4];
        oacc[mt] = MFMA16(a, pb, oacc[mt]);
      }
    }
    wcur = wnext;
    j0 = j0n;
  }

  // epilogue: normalize, transpose via LDS, coalesced ctx write
  float inv_l = 1.0f / lacc[0];
#pragma unroll
  for (int mt = 0; mt < 4; ++mt)
#pragma unroll
    for (int r = 0; r < 4; ++r)
      ot[(wave * 16 + c) * 72 + mt * 16 + 4 * q + r] = (half_t)(oacc[mt][r] * inv_l);
  __syncthreads();
  {
    int row = tid >> 2, chq = tid & 3;  // 128 rows x 4 chunk-pairs
    int b = bh >> 4, h = bh & 15;
    size_t base = (((size_t)(b * SEQ + i0 + row) * NH) + h) * 64 + chq * 16;
    half8 v0 = *(const half8*)&ot[row * 72 + chq * 16];
    half8 v1 = *(const half8*)&ot[row * 72 + chq * 16 + 8];
    *(half8*)(ctx + base) = v0;
    *(half8*)(ctx + base + 8) = v1;
  }
}

// ---------------- launch -----------------------------------------------------
extern "C" void kernel_launch(void* const* d_in, const int* in_sizes, int n_in,
                              void* d_out, int out_size, void* d_ws, size_t ws_size,
                              hipStream_t stream) {
  const float* query = (const float*)d_in[0];
  const float* key_value = (const float*)d_in[1];
  const float* Wq = (const float*)d_in[2];
  const float* bq = (const float*)d_in[3];
  const float* Wkv = (const float*)d_in[4];
  const float* bkv = (const float*)d_in[5];
  const float* Wo = (const float*)d_in[6];
  const float* bo = (const float*)d_in[7];

  char* ws = (char*)d_ws;
  uint8_t* tok = (uint8_t*)ws;               // 64
  uint8_t* tok16 = (uint8_t*)(ws + 1024);    // 256
  uint64_t* maskw = (uint64_t*)(ws + 4096);  // 32KB
  const size_t MB = 1ull << 20;
  half_t* xq = (half_t*)(ws + 1 * MB);    // 8MB; reused as ctx after qkv gemm
  half_t* xkv = (half_t*)(ws + 9 * MB);   // 8MB
  half_t* wqT = (half_t*)(ws + 17 * MB);  // 2MB
  half_t* wkvT = (half_t*)(ws + 19 * MB); // 4MB
  half_t* woT = (half_t*)(ws + 23 * MB);  // 2MB
  half_t* qbuf = (half_t*)(ws + 25 * MB); // 8MB
  half_t* kbuf = (half_t*)(ws + 33 * MB); // 8MB
  half_t* vTg = (half_t*)(ws + 41 * MB);  // 8MB ([bh][d][s])
  half_t* ctx = xq;                       // alias (xq dead after proj)

  hipLaunchKernelGGL(prep, dim3(4112), dim3(256), 0, stream,
                     query, key_value, Wq, Wkv, Wo, xq, xkv, wqT, wkvT, woT,
                     tok, tok16, maskw);
  hipLaunchKernelGGL(gemm_qkv, dim3(32, 24), dim3(256), 49152, stream,
                     xq, xkv, wqT, wkvT, bq, bkv, qbuf, kbuf, vTg);
  hipLaunchKernelGGL(attn_kernel, dim3(512), dim3(512), 0, stream,
                     qbuf, kbuf, vTg, ctx, maskw, tok, tok16);
  hipLaunchKernelGGL(gemm_out, dim3(32, 16), dim3(256), 0, stream,
                     ctx, woT, bo, (float*)d_out);
}